// Round 4
// baseline (180.001 us; speedup 1.0000x reference)
//
#include <hip/hip_runtime.h>
#include <math.h>

// ---------------- workspace layout (float offsets) ----------------
#define OFF_W2P 0              // [64][224]  Wm2 pre-contracted with P
#define OFF_B2P 14336          // [224]
#define WS_FLOATS 14560

#define SC_Y0 0.0180421959121758f   // (1/sqrt(32))*(1/sqrt(96))
#define SC_Y2 0.015625f             // (1/sqrt(32))*(1/sqrt(128))
#define S2f 0.70710678118654752f
#define S6f 0.40824829046386302f
#define TWOS2f 1.41421356237309505f
#define TWOS6f 0.81649658092772603f
#define ISQRT3 0.57735026918962576f
#define ISQRT5 0.44721359549995794f
#define H0SC 0.08838834764831845f   // 1/sqrt(128)
#define H1SC 0.125f                 // 1/sqrt(64)
#define H2SC 0.17677669529663689f   // 1/sqrt(32)

__device__ __constant__ int KARR[7] = {0, 1, 2, 4, 5, 6, 8};

// ---------------- prep: Wm2p, bm2p, zero out ----------------
__global__ __launch_bounds__(256) void prep_kernel(
    const float* __restrict__ Wm2, const float* __restrict__ bm2,
    const float* __restrict__ P0, const float* __restrict__ P2,
    float* __restrict__ ws, float* __restrict__ out) {
  int j = blockIdx.x * 256 + threadIdx.x;
  if (j < 2304) out[j] = 0.f;

  if (j < 14336) {
    int s = j >> 11; int rem = j & 2047; int c = rem >> 5; int u = rem & 31;
    int k = KARR[s];
    const float* P;
    float sc;
    switch (s) {
      case 0: P = P0;      sc = SC_Y0; break;
      case 1: P = P2;      sc = SC_Y2; break;
      case 2: P = P0 + 32; sc = SC_Y0; break;
      case 3: P = P2 + 32; sc = SC_Y2; break;
      case 4: P = P2 + 64; sc = SC_Y2; break;
      case 5: P = P0 + 64; sc = SC_Y0; break;
      default: P = P2 + 96; sc = SC_Y2; break;
    }
    const float4* w4 = (const float4*)(Wm2 + c * 9216 + k * 1024 + u * 32);
    const float4* p4 = (const float4*)P;
    float acc = 0.f;
#pragma unroll
    for (int q = 0; q < 8; ++q) {
      float4 a = w4[q], b = p4[q];
      acc += a.x * b.x + a.y * b.y + a.z * b.z + a.w * b.w;
    }
    ws[OFF_W2P + c * 224 + s * 32 + u] = acc * sc;
  } else if (j < 14560) {
    int i = j - 14336; int s = i >> 5; int u = i & 31; int k = KARR[s];
    const float* P;
    float sc;
    switch (s) {
      case 0: P = P0;      sc = SC_Y0; break;
      case 1: P = P2;      sc = SC_Y2; break;
      case 2: P = P0 + 32; sc = SC_Y0; break;
      case 3: P = P2 + 32; sc = SC_Y2; break;
      case 4: P = P2 + 64; sc = SC_Y2; break;
      case 5: P = P0 + 64; sc = SC_Y0; break;
      default: P = P2 + 96; sc = SC_Y2; break;
    }
    const float* b = bm2 + k * 1024 + u * 32;
    float acc = 0.f;
#pragma unroll
    for (int w = 0; w < 32; ++w) acc += b[w] * P[w];
    ws[OFF_B2P + s * 32 + u] = acc * sc;
  }
}

// ---------------- fused: 16 nodes/block, everything in LDS ----------------
// LDS (bytes):
//   [0,     30976)  xp[16][484]  (x_sph tile; row stride 484 => banks 4(n+m)%32, conflict-free)
//   [30976, 45312)  V[16][224]   (phase-3 output)  -- xs[16][132] overlays here phases 0-2
//   [45312, 49664)  hiT[64][17]  (stride 17 => conflict-free transposed writes)
//   [49664, 50048)  sphs[16][6]
//   [50048, 50112)  batch_s[16]
__global__ __launch_bounds__(256) void fused_kernel(
    const float* __restrict__ xs_g, const float* __restrict__ xsph,
    const int* __restrict__ batch,
    const float* __restrict__ W0e, const float* __restrict__ W1o,
    const float* __restrict__ W2e,
    const float* __restrict__ Wm1, const float* __restrict__ bm1,
    const float* __restrict__ ws, float* __restrict__ out, const float norm2) {
  __shared__ __align__(16) char smem[50112];
  float (*xp)[484] = (float (*)[484])smem;
  float* Vb        = (float*)(smem + 30976);
  float (*xs)[132] = (float (*)[132])(smem + 30976);
  float (*hiT)[17] = (float (*)[17])(smem + 45312);
  float (*sphs)[6] = (float (*)[6])(smem + 49664);
  int* batch_s     = (int*)(smem + 50048);

  const int tid = threadIdx.x;
  const int n0 = blockIdx.x * 16;   // 1250 * 16 == 20000 exactly

  // ---- phase 0: stage x_sph + x_scalar + batch (all loads in flight early) ----
  for (int idx = tid; idx < 1920; idx += 256) {
    const int row = idx / 120, c4 = idx % 120;
    *(float4*)&xp[row][c4 * 4] =
        *(const float4*)(xsph + (size_t)(n0 + row) * 480 + c4 * 4);
  }
  for (int idx = tid; idx < 512; idx += 256) {
    const int row = idx >> 5, c4 = idx & 31;
    *(float4*)&xs[row][c4 * 4] =
        *(const float4*)(xs_g + (n0 + row) * 128 + c4 * 4);
  }
  if (tid < 16) batch_s[tid] = batch[n0 + tid];
  __syncthreads();

  // ---- phase 1: hidden[c][n] = silu(x_scalar @ Wm1 + bm1), transposed in hiT ----
  {
    const int n = tid >> 4, c0 = (tid & 15) * 4;
    float acc[4] = {0.f, 0.f, 0.f, 0.f};
#pragma unroll 4
    for (int mq = 0; mq < 32; ++mq) {
      const float4 xv = *(float4*)&xs[n][mq * 4];
      const float xa[4] = {xv.x, xv.y, xv.z, xv.w};
#pragma unroll
      for (int r = 0; r < 4; ++r) {
        const float4 w = *(const float4*)(Wm1 + (mq * 4 + r) * 64 + c0);
        acc[0] += xa[r] * w.x; acc[1] += xa[r] * w.y;
        acc[2] += xa[r] * w.z; acc[3] += xa[r] * w.w;
      }
    }
    const float4 bb = *(const float4*)(bm1 + c0);
    const float bv[4] = {bb.x, bb.y, bb.z, bb.w};
#pragma unroll
    for (int jj = 0; jj < 4; ++jj) {
      float z = acc[jj] + bv[jj];
      hiT[c0 + jj][n] = z / (1.f + __expf(-z));
    }
  }
  __syncthreads();

  // ---- phase 2: V[n][o] = hidden @ W2p + b2p  (V overlays dead xs region) ----
  if (tid < 224) {
    const int og = tid >> 3, ng = tid & 7;
    const int o0 = og * 8, n = ng * 2;
    const float4 blo = *(const float4*)(ws + OFF_B2P + o0);
    const float4 bhi = *(const float4*)(ws + OFF_B2P + o0 + 4);
    float acc[2][8];
#pragma unroll
    for (int i = 0; i < 2; ++i) {
      acc[i][0] = blo.x; acc[i][1] = blo.y; acc[i][2] = blo.z; acc[i][3] = blo.w;
      acc[i][4] = bhi.x; acc[i][5] = bhi.y; acc[i][6] = bhi.z; acc[i][7] = bhi.w;
    }
#pragma unroll 2
    for (int c = 0; c < 64; ++c) {
      const float h0v = hiT[c][n], h1v = hiT[c][n + 1];
      const float4 wlo = *(const float4*)(ws + OFF_W2P + c * 224 + o0);
      const float4 whi = *(const float4*)(ws + OFF_W2P + c * 224 + o0 + 4);
      const float wv[8] = {wlo.x, wlo.y, wlo.z, wlo.w, whi.x, whi.y, whi.z, whi.w};
#pragma unroll
      for (int jj = 0; jj < 8; ++jj) {
        acc[0][jj] += h0v * wv[jj];
        acc[1][jj] += h1v * wv[jj];
      }
    }
#pragma unroll
    for (int i = 0; i < 2; ++i) {
      float4 a = {acc[i][0], acc[i][1], acc[i][2], acc[i][3]};
      float4 b = {acc[i][4], acc[i][5], acc[i][6], acc[i][7]};
      *(float4*)&Vb[(n + i) * 224 + o0] = a;
      *(float4*)&Vb[(n + i) * 224 + o0 + 4] = b;
    }
  }
  __syncthreads();

  // ---- phase 3: h-projections (per n, 2 u's) + path math + 16-lane reduce ----
  {
    const int n = tid >> 4, ug = tid & 15;
    const int u0 = ug * 2;
    float h0acc[2] = {0.f, 0.f};
    float h1acc[3][2] = {{0.f}};
    float h2acc[5][2] = {{0.f}};

    // h0: K=128
#pragma unroll 4
    for (int mq = 0; mq < 32; ++mq) {
      const float4 xv = *(float4*)&xp[n][mq * 4];
      const float xa[4] = {xv.x, xv.y, xv.z, xv.w};
#pragma unroll
      for (int r = 0; r < 4; ++r) {
        const float2 w = *(const float2*)(W0e + (mq * 4 + r) * 32 + u0);
        h0acc[0] += xa[r] * w.x;
        h0acc[1] += xa[r] * w.y;
      }
    }
    // h1: K=64, 3 components
#pragma unroll 2
    for (int mq = 0; mq < 16; ++mq) {
      const float4 a0 = *(float4*)&xp[n][128 + mq * 12];
      const float4 a1 = *(float4*)&xp[n][128 + mq * 12 + 4];
      const float4 a2 = *(float4*)&xp[n][128 + mq * 12 + 8];
      const float xa[12] = {a0.x, a0.y, a0.z, a0.w, a1.x, a1.y, a1.z, a1.w,
                            a2.x, a2.y, a2.z, a2.w};
#pragma unroll
      for (int mm = 0; mm < 4; ++mm) {
        const float2 w = *(const float2*)(W1o + (mq * 4 + mm) * 32 + u0);
#pragma unroll
        for (int j = 0; j < 3; ++j) {
          h1acc[j][0] += xa[mm * 3 + j] * w.x;
          h1acc[j][1] += xa[mm * 3 + j] * w.y;
        }
      }
    }
    // h2: K=32, 5 components
#pragma unroll 2
    for (int mq = 0; mq < 8; ++mq) {
      const float4 a0 = *(float4*)&xp[n][320 + mq * 20];
      const float4 a1 = *(float4*)&xp[n][320 + mq * 20 + 4];
      const float4 a2 = *(float4*)&xp[n][320 + mq * 20 + 8];
      const float4 a3 = *(float4*)&xp[n][320 + mq * 20 + 12];
      const float4 a4 = *(float4*)&xp[n][320 + mq * 20 + 16];
      const float xa[20] = {a0.x, a0.y, a0.z, a0.w, a1.x, a1.y, a1.z, a1.w,
                            a2.x, a2.y, a2.z, a2.w, a3.x, a3.y, a3.z, a3.w,
                            a4.x, a4.y, a4.z, a4.w};
#pragma unroll
      for (int mm = 0; mm < 4; ++mm) {
        const float2 w = *(const float2*)(W2e + (mq * 4 + mm) * 32 + u0);
#pragma unroll
        for (int j = 0; j < 5; ++j) {
          h2acc[j][0] += xa[mm * 5 + j] * w.x;
          h2acc[j][1] += xa[mm * 5 + j] * w.y;
        }
      }
    }

    float y0s = 0.f, y2s[5] = {0.f, 0.f, 0.f, 0.f, 0.f};
    const float* Vn = Vb + n * 224 + u0;
#pragma unroll
    for (int uu = 0; uu < 2; ++uu) {
      const float h0 = h0acc[uu] * H0SC;
      const float h1a = h1acc[0][uu] * H1SC;
      const float h1b = h1acc[1][uu] * H1SC;
      const float h1c = h1acc[2][uu] * H1SC;
      float h2v[5];
#pragma unroll
      for (int j = 0; j < 5; ++j) h2v[j] = h2acc[j][uu] * H2SC;

      const float v0 = Vn[uu],       v1 = Vn[32 + uu],
                  v2 = Vn[64 + uu],  v3 = Vn[96 + uu],
                  v4 = Vn[128 + uu], v5 = Vn[160 + uu],
                  v6 = Vn[192 + uu];

      const float d11 = h1a * h1a + h1b * h1b + h1c * h1c;
      const float d22 = h2v[0] * h2v[0] + h2v[1] * h2v[1] + h2v[2] * h2v[2] +
                        h2v[3] * h2v[3] + h2v[4] * h2v[4];
      y0s += v0 * h0 * h0 + v2 * d11 * ISQRT3 + v5 * d22 * ISQRT5;

      const float o00 = h1a * h1a, o01 = h1a * h1b, o02 = h1a * h1c;
      const float o11 = h1b * h1b, o12 = h1b * h1c, o22 = h1c * h1c;
      const float t40 = TWOS2f * o01, t41 = TWOS2f * o12;
      const float t42 = S6f * (2.f * o22 - o00 - o11);
      const float t43 = TWOS2f * o02, t44 = S2f * (o00 - o11);

      const float A00 = -S6f * h2v[2] + S2f * h2v[4];
      const float A01 = S2f * h2v[0];
      const float A02 = S2f * h2v[3];
      const float A11 = -S6f * h2v[2] - S2f * h2v[4];
      const float A12 = S2f * h2v[1];
      const float A22 = TWOS6f * h2v[2];
      const float B00 = A00 * A00 + A01 * A01 + A02 * A02;
      const float B01 = A00 * A01 + A01 * A11 + A02 * A12;
      const float B02 = A00 * A02 + A01 * A12 + A02 * A22;
      const float B11 = A01 * A01 + A11 * A11 + A12 * A12;
      const float B12 = A01 * A02 + A11 * A12 + A12 * A22;
      const float B22 = A02 * A02 + A12 * A12 + A22 * A22;
      const float t80 = TWOS2f * B01, t81 = TWOS2f * B12;
      const float t82 = S6f * (2.f * B22 - B00 - B11);
      const float t83 = TWOS2f * B02, t84 = S2f * (B00 - B11);

      const float w15 = (v1 + v4) * h0;
      const float v6n = v6 * norm2;
      y2s[0] += w15 * h2v[0] + v3 * t40 + v6n * t80;
      y2s[1] += w15 * h2v[1] + v3 * t41 + v6n * t81;
      y2s[2] += w15 * h2v[2] + v3 * t42 + v6n * t82;
      y2s[3] += w15 * h2v[3] + v3 * t43 + v6n * t83;
      y2s[4] += w15 * h2v[4] + v3 * t44 + v6n * t84;
    }

#pragma unroll
    for (int off = 1; off < 16; off <<= 1) {
      y0s += __shfl_xor(y0s, off, 64);
#pragma unroll
      for (int r = 0; r < 5; ++r) y2s[r] += __shfl_xor(y2s[r], off, 64);
    }
    if (ug == 0) {
      sphs[n][0] = y0s;
#pragma unroll
      for (int r = 0; r < 5; ++r) sphs[n][1 + r] = y2s[r];
    }
  }
  __syncthreads();

  // ---- phase 4: cart + segment-merged atomics ----
  if (tid < 9) {
    const float QW[9][6] = {
        {ISQRT3, 0.f, 0.f, -S6f, 0.f, S2f},
        {0.f, S2f, 0.f, 0.f, 0.f, 0.f},
        {0.f, 0.f, 0.f, 0.f, S2f, 0.f},
        {0.f, S2f, 0.f, 0.f, 0.f, 0.f},
        {ISQRT3, 0.f, 0.f, -S6f, 0.f, -S2f},
        {0.f, 0.f, S2f, 0.f, 0.f, 0.f},
        {0.f, 0.f, 0.f, 0.f, S2f, 0.f},
        {0.f, 0.f, S2f, 0.f, 0.f, 0.f},
        {ISQRT3, 0.f, 0.f, TWOS6f, 0.f, 0.f}};
    const int a = tid / 3, b = tid % 3;
    const int rolled = ((a + 1) % 3) * 3 + ((b + 1) % 3);
    const float c0 = QW[tid][0], c1 = QW[tid][1], c2 = QW[tid][2];
    const float c3 = QW[tid][3], c4 = QW[tid][4], c5 = QW[tid][5];
    int cur_g = batch_s[0];
    float acc = 0.f;
#pragma unroll 4
    for (int q = 0; q < 16; ++q) {
      const int g = batch_s[q];
      const float val = c0 * sphs[q][0] + c1 * sphs[q][1] + c2 * sphs[q][2] +
                        c3 * sphs[q][3] + c4 * sphs[q][4] + c5 * sphs[q][5];
      if (g != cur_g) {
        atomicAdd(out + cur_g * 9 + rolled, acc);
        acc = 0.f;
        cur_g = g;
      }
      acc += val;
    }
    atomicAdd(out + cur_g * 9 + rolled, acc);
  }
}

extern "C" void kernel_launch(void* const* d_in, const int* in_sizes, int n_in,
                              void* d_out, int out_size, void* d_ws, size_t ws_size,
                              hipStream_t stream) {
  const float* x_scalar = (const float*)d_in[0];
  const float* x_sph    = (const float*)d_in[1];
  const int*   batch    = (const int*)d_in[2];
  const float* W0e      = (const float*)d_in[3];
  const float* W1o      = (const float*)d_in[4];
  const float* W2e      = (const float*)d_in[5];
  const float* Wm1      = (const float*)d_in[6];
  const float* bm1      = (const float*)d_in[7];
  const float* Wm2      = (const float*)d_in[8];
  const float* bm2      = (const float*)d_in[9];
  const float* P0       = (const float*)d_in[10];
  // P1 (d_in[11]) provably unused: C111/C221 antisymmetric vs h(x)h of same h.
  const float* P2       = (const float*)d_in[12];
  float* ws  = (float*)d_ws;
  float* out = (float*)d_out;

  if (ws_size < (size_t)WS_FLOATS * sizeof(float)) return;

  // host-side C222 normalization (pure CPU double math; = sqrt(12/7))
  double Q2[5][3][3] = {};
  const double s2d = 0.70710678118654752440, s6d = 0.40824829046386301637;
  Q2[0][0][1] = Q2[0][1][0] = s2d;
  Q2[1][1][2] = Q2[1][2][1] = s2d;
  Q2[2][0][0] = Q2[2][1][1] = -s6d; Q2[2][2][2] = 2.0 * s6d;
  Q2[3][0][2] = Q2[3][2][0] = s2d;
  Q2[4][0][0] = s2d; Q2[4][1][1] = -s2d;
  double ss = 0.0;
  for (int i = 0; i < 5; ++i)
    for (int jj = 0; jj < 5; ++jj) {
      double S[3][3];
      for (int a = 0; a < 3; ++a)
        for (int d = 0; d < 3; ++d) {
          double m1 = 0, m2 = 0;
          for (int b = 0; b < 3; ++b) {
            m1 += Q2[i][a][b] * Q2[jj][d][b];
            m2 += Q2[i][d][b] * Q2[jj][a][b];
          }
          S[a][d] = 0.5 * (m1 + m2);
        }
      double tr = (S[0][0] + S[1][1] + S[2][2]) / 3.0;
      S[0][0] -= tr; S[1][1] -= tr; S[2][2] -= tr;
      for (int kk = 0; kk < 5; ++kk) {
        double cc = 0;
        for (int a = 0; a < 3; ++a)
          for (int d = 0; d < 3; ++d) cc += Q2[kk][a][d] * S[a][d];
        ss += cc * cc;
      }
    }
  const float norm2 = (float)sqrt(5.0 / ss);

  prep_kernel<<<57, 256, 0, stream>>>(Wm2, bm2, P0, P2, ws, out);
  fused_kernel<<<1250, 256, 0, stream>>>(x_scalar, x_sph, batch, W0e, W1o, W2e,
                                         Wm1, bm1, ws, out, norm2);
}